// Round 6
// baseline (310.870 us; speedup 1.0000x reference)
//
#include <hip/hip_runtime.h>
#include <math.h>

// Problem constants (compile-time fixed)
#define NB   2
#define LQ   13294
#define NROWS (NB*LQ)      // 26588
#define CDIM 256

typedef unsigned short u16;
typedef unsigned int   u32;
typedef short bf16x8 __attribute__((ext_vector_type(8)));
typedef float f32x4  __attribute__((ext_vector_type(4)));

struct alignas(8) U16x4 { u16 x, y, z, w; };

__device__ __forceinline__ u16 f2bf(float f) {   // round-to-nearest-even
    u32 u = __builtin_bit_cast(u32, f);
    u += 0x7FFFu + ((u >> 16) & 1u);
    return (u16)(u >> 16);
}

// Weights -> one bf16 region: [Wv 65536][Woff 65536][Wa 32768][Wo 65536]
// (Woff++Wa contiguous = the 384-row fused B). Also bcat = boff++ba (384).
__global__ __launch_bounds__(256)
void prep_weights(const float* __restrict__ Wv, const float* __restrict__ Woff,
                  const float* __restrict__ Wa, const float* __restrict__ Wo,
                  const float* __restrict__ boff, const float* __restrict__ ba,
                  u16* __restrict__ dst, float* __restrict__ biascat) {
    int i = blockIdx.x * 256 + threadIdx.x;
    float v;
    if      (i <  65536) v = Wv[i];
    else if (i < 131072) v = Woff[i - 65536];
    else if (i < 163840) v = Wa[i - 131072];
    else                 v = Wo[i - 163840];
    dst[i] = f2bf(v);
    if (blockIdx.x == 0) {
        int t = threadIdx.x;
        biascat[t] = boff[t];
        if (t < 128) biascat[256 + t] = ba[t];
    }
}

// Persistent-B skinny-K GEMM: C[r][c] = sum_k A[r][k]*B[c][k] + bias[c].
// K=256. Block = 4 waves, 128x128 tile. B-slab (128 cols x 256 k bf16, 64 KB)
// staged into LDS ONCE with XOR chunk swizzle (kills 16-way bank conflict);
// each wave holds its 64-row A strip fully in registers (fp32->bf16 in-reg
// when ABF16==false); single barrier. SPLIT: cols >= 256 -> C1 (ld 128).
template<bool ABF16, bool SPLIT>
__global__ __launch_bounds__(256, 2)
void gemm_persist(const void* __restrict__ Av, const u16* __restrict__ B,
                  const float* __restrict__ bias, float* __restrict__ C0,
                  float* __restrict__ C1, int M) {
    __shared__ u16 Bs[128 * 256];      // 64 KB, [c][chunk-swizzled k]
    const int tid  = threadIdx.x;
    const int wave = tid >> 6;
    const int lane = tid & 63;
    const int ln16 = lane & 15;
    const int kq   = lane >> 4;            // 0..3
    const int col0 = blockIdx.x * 128;
    const int row0 = blockIdx.y * 128;
    const int wr   = (wave >> 1) * 64;
    const int wc   = (wave & 1) * 64;

    // stage B slab: 4096 16B chunks, coalesced; chunk index XOR-swizzled
    #pragma unroll
    for (int it = 0; it < 16; ++it) {
        int g  = it * 256 + tid;
        int c  = g >> 5;                   // slab col
        int ch = g & 31;                   // 16B chunk in row
        float4 v = *(const float4*)(B + (size_t)(col0 + c) * 256 + ch * 8);
        *(float4*)&Bs[c * 256 + (ch ^ (c & 7)) * 8] = v;
    }

    // A strip: 4 row-tiles x full K in registers
    bf16x8 a[4][8];
    #pragma unroll
    for (int i = 0; i < 4; ++i) {
        int gr = min(row0 + wr + i * 16 + ln16, M - 1);
        if (ABF16) {
            const u16* Ap = (const u16*)Av + (size_t)gr * 256 + kq * 8;
            #pragma unroll
            for (int kt = 0; kt < 8; ++kt)
                a[i][kt] = *(const bf16x8*)(Ap + kt * 32);
        } else {
            const float* Ap = (const float*)Av + (size_t)gr * 256 + kq * 8;
            #pragma unroll
            for (int kt = 0; kt < 8; ++kt) {
                float4 lo = *(const float4*)(Ap + kt * 32);
                float4 hi = *(const float4*)(Ap + kt * 32 + 4);
                union { u16 h[8]; bf16x8 v; } u;
                u.h[0] = f2bf(lo.x); u.h[1] = f2bf(lo.y);
                u.h[2] = f2bf(lo.z); u.h[3] = f2bf(lo.w);
                u.h[4] = f2bf(hi.x); u.h[5] = f2bf(hi.y);
                u.h[6] = f2bf(hi.z); u.h[7] = f2bf(hi.w);
                a[i][kt] = u.v;
            }
        }
    }
    __syncthreads();

    f32x4 acc[4][4] = {};
    #pragma unroll
    for (int kt = 0; kt < 8; ++kt) {
        bf16x8 b[4];
        #pragma unroll
        for (int j = 0; j < 4; ++j) {
            int c2 = wc + j * 16 + ln16;
            b[j] = *(const bf16x8*)&Bs[c2 * 256 + ((kt * 4 + kq) ^ (c2 & 7)) * 8];
        }
        #pragma unroll
        for (int i = 0; i < 4; ++i)
            #pragma unroll
            for (int j = 0; j < 4; ++j)
                acc[i][j] = __builtin_amdgcn_mfma_f32_16x16x32_bf16(
                    a[i][kt], b[j], acc[i][j], 0, 0, 0);
    }

    // C/D layout: col = lane&15, row = kq*4 + reg
    #pragma unroll
    for (int j = 0; j < 4; ++j) {
        int gc = col0 + wc + j * 16 + ln16;
        float bj = bias[gc];
        #pragma unroll
        for (int i = 0; i < 4; ++i) {
            int gr0 = row0 + wr + i * 16 + kq * 4;
            #pragma unroll
            for (int r = 0; r < 4; ++r) {
                int gr = gr0 + r;
                if (gr < M) {
                    if (SPLIT && gc >= 256)
                        C1[(size_t)gr * 128 + (gc - 256)] = acc[i][j][r] + bj;
                    else
                        C0[(size_t)gr * 256 + gc] = acc[i][j][r] + bj;
                }
            }
        }
    }
}

// Sampler: 4 queries per block. Phase A: 32 threads do the 32 (q,m) softmaxes.
// Phase B: 512 point-jobs (q,m,l,p) computed ONCE each -> LDS descriptors
// (4 clamped absolute value-row indices + 4 validity/attn-folded weights).
// Phase C: (q,m,e) lanes gather float4 channels using LDS descriptors.
__global__ __launch_bounds__(256)
void msda_sample(const float* __restrict__ value,    // (NB*LQ, 256) fp32
                 const float* __restrict__ refpts,   // (NB*LQ, 4, 2)
                 const float* __restrict__ off,      // (NB*LQ, 256) fp32
                 const float* __restrict__ logits,   // (NB*LQ, 128) fp32
                 u16* __restrict__ tmp) {            // (NB*LQ, 256) bf16
    __shared__ float sAw[4][8][16];
    __shared__ int   sLin[4][8][17][4];   // [17] pad: conflict-free m-groups
    __shared__ float sW[4][8][17][4];

    const int t  = threadIdx.x;
    const int qb = blockIdx.x * 4;

    // ---- Phase A: softmax per (q,m) ----
    if (t < 32) {
        const int qi = t >> 3, m = t & 7;
        const float* lg = logits + (size_t)(qb + qi) * 128 + m * 16;
        float e[16];
        float mx = -1e30f;
        #pragma unroll
        for (int i = 0; i < 16; ++i) { e[i] = lg[i]; mx = fmaxf(mx, e[i]); }
        float s = 0.f;
        #pragma unroll
        for (int i = 0; i < 16; ++i) { e[i] = __expf(e[i] - mx); s += e[i]; }
        const float inv = 1.f / s;
        #pragma unroll
        for (int i = 0; i < 16; ++i) sAw[qi][m][i] = e[i] * inv;
    }
    __syncthreads();

    // ---- Phase B: 512 point jobs, 2 per thread ----
    #pragma unroll
    for (int j2 = 0; j2 < 2; ++j2) {
        const int job = t + j2 * 256;
        const int qi = job >> 7;            // 128 jobs per query
        const int m  = (job >> 4) & 7;
        const int p  = job & 15;
        const int l  = p >> 2, pp = p & 3;
        const int q  = qb + qi;
        const int n  = (q >= LQ) ? 1 : 0;

        const int W = (l == 0) ? 100 : (l == 1) ? 50 : (l == 2) ? 25 : 13;
        const int H = W;
        const int st = (l == 0) ? 0 : (l == 1) ? 10000 : (l == 2) ? 12500 : 13125;

        const float rx = refpts[(size_t)q * 8 + l * 2 + 0];
        const float ry = refpts[(size_t)q * 8 + l * 2 + 1];
        const float ox = off[(size_t)q * 256 + m * 32 + (l * 4 + pp) * 2 + 0];
        const float oy = off[(size_t)q * 256 + m * 32 + (l * 4 + pp) * 2 + 1];

        // replicate reference arithmetic order
        const float locx = rx + ox / (float)W;
        const float locy = ry + oy / (float)H;
        const float grx = 2.f * locx - 1.f;
        const float gry = 2.f * locy - 1.f;
        const float gx = ((grx + 1.f) * (float)W - 1.f) * 0.5f;
        const float gy = ((gry + 1.f) * (float)H - 1.f) * 0.5f;
        const float x0f = floorf(gx), y0f = floorf(gy);
        const float fx = gx - x0f, fy = gy - y0f;
        const int x0 = (int)x0f, y0 = (int)y0f;
        const int x1 = x0 + 1, y1 = y0 + 1;

        const int cx0 = min(max(x0, 0), W - 1);
        const int cx1 = min(max(x1, 0), W - 1);
        const int cy0 = min(max(y0, 0), H - 1);
        const int cy1 = min(max(y1, 0), H - 1);
        const bool vx0 = (x0 >= 0) & (x0 < W);
        const bool vx1 = (x1 >= 0) & (x1 < W);
        const bool vy0 = (y0 >= 0) & (y0 < H);
        const bool vy1 = (y1 >= 0) & (y1 < H);

        const float aw = sAw[qi][m][p];
        const int base = n * LQ + st;
        sLin[qi][m][p][0] = base + cy0 * W + cx0;
        sLin[qi][m][p][1] = base + cy0 * W + cx1;
        sLin[qi][m][p][2] = base + cy1 * W + cx0;
        sLin[qi][m][p][3] = base + cy1 * W + cx1;
        sW[qi][m][p][0] = (vy0 & vx0) ? aw * (1.f - fy) * (1.f - fx) : 0.f;
        sW[qi][m][p][1] = (vy0 & vx1) ? aw * (1.f - fy) * fx         : 0.f;
        sW[qi][m][p][2] = (vy1 & vx0) ? aw * fy * (1.f - fx)         : 0.f;
        sW[qi][m][p][3] = (vy1 & vx1) ? aw * fy * fx                 : 0.f;
    }
    __syncthreads();

    // ---- Phase C: gather ----
    const int qi = t >> 6;
    const int m  = (t >> 3) & 7;
    const int e  = t & 7;
    const int q  = qb + qi;
    const float* vch = value + m * 32 + e * 4;

    float ax = 0.f, ay = 0.f, az = 0.f, aw_ = 0.f;
    #pragma unroll
    for (int p = 0; p < 16; ++p) {
        int4   L  = *(const int4*)&sLin[qi][m][p][0];
        float4 Wt = *(const float4*)&sW[qi][m][p][0];
        float4 c00 = *(const float4*)(vch + (size_t)L.x * 256);
        float4 c01 = *(const float4*)(vch + (size_t)L.y * 256);
        float4 c10 = *(const float4*)(vch + (size_t)L.z * 256);
        float4 c11 = *(const float4*)(vch + (size_t)L.w * 256);
        ax  += Wt.x * c00.x + Wt.y * c01.x + Wt.z * c10.x + Wt.w * c11.x;
        ay  += Wt.x * c00.y + Wt.y * c01.y + Wt.z * c10.y + Wt.w * c11.y;
        az  += Wt.x * c00.z + Wt.y * c01.z + Wt.z * c10.z + Wt.w * c11.z;
        aw_ += Wt.x * c00.w + Wt.y * c01.w + Wt.z * c10.w + Wt.w * c11.w;
    }
    U16x4 o{f2bf(ax), f2bf(ay), f2bf(az), f2bf(aw_)};
    *(U16x4*)&tmp[(size_t)q * 256 + m * 32 + e * 4] = o;
}

extern "C" void kernel_launch(void* const* d_in, const int* in_sizes, int n_in,
                              void* d_out, int out_size, void* d_ws, size_t ws_size,
                              hipStream_t stream) {
    const float* query  = (const float*)d_in[0];
    const float* refpts = (const float*)d_in[1];
    const float* inflat = (const float*)d_in[2];
    const float* Wv   = (const float*)d_in[5];
    const float* bv   = (const float*)d_in[6];
    const float* Woff = (const float*)d_in[7];
    const float* boff = (const float*)d_in[8];
    const float* Wa   = (const float*)d_in[9];
    const float* ba   = (const float*)d_in[10];
    const float* Wo   = (const float*)d_in[11];
    const float* bo   = (const float*)d_in[12];
    float* out = (float*)d_out;

    // workspace layout (~82 MB)
    char* ws = (char*)d_ws;
    constexpr size_t SZ32 = (size_t)NROWS * 256 * 4;            // 27,226,112
    constexpr size_t SZL  = (size_t)NROWS * 128 * 4;            // 13,613,056
    constexpr size_t SZ16 = (size_t)NROWS * 256 * 2;            // 13,613,056
    float* value = (float*)(ws);
    float* offb  = (float*)(ws + SZ32);
    float* logit = (float*)(ws + 2 * SZ32);
    u16*   tmp   = (u16*)(ws + 2 * SZ32 + SZL);
    u16*   wb    = (u16*)(ws + 2 * SZ32 + SZL + SZ16);
    float* bcat  = (float*)(ws + 2 * SZ32 + SZL + SZ16 + 229376 * 2);

    dim3 blk(256);
    hipLaunchKernelGGL(prep_weights, dim3(896), blk, 0, stream,
                       Wv, Woff, Wa, Wo, boff, ba, wb, bcat);

    // value = inflat @ Wv^T + bv   (fp32 A, in-register bf16 convert)
    gemm_persist<false, false><<<dim3(2, 208), blk, 0, stream>>>(
        inflat, wb, bv, value, nullptr, NROWS);
    // [offb | logit] = query @ [Woff;Wa]^T + [boff;ba]
    gemm_persist<false, true><<<dim3(3, 208), blk, 0, stream>>>(
        query, wb + 65536, bcat, offb, logit, NROWS);

    hipLaunchKernelGGL(msda_sample, dim3(NROWS / 4), blk, 0, stream,
                       value, refpts, offb, logit, tmp);

    // out = tmp @ Wo^T + bo   (bf16 A)
    gemm_persist<true, false><<<dim3(2, 208), blk, 0, stream>>>(
        tmp, wb + 163840, bo, out, nullptr, NROWS);
}

// Round 7
// 267.232 us; speedup vs baseline: 1.1633x; 1.1633x over previous
//
#include <hip/hip_runtime.h>
#include <math.h>

// Problem constants (compile-time fixed)
#define NB   2
#define LQ   13294
#define NROWS (NB*LQ)      // 26588
#define CDIM 256

typedef unsigned short u16;
typedef unsigned int   u32;
typedef short bf16x8 __attribute__((ext_vector_type(8)));
typedef float f32x4  __attribute__((ext_vector_type(4)));

struct alignas(8) U16x4 { u16 x, y, z, w; };

__device__ __forceinline__ u16 f2bf(float f) {   // round-to-nearest-even
    u32 u = __builtin_bit_cast(u32, f);
    u += 0x7FFFu + ((u >> 16) & 1u);
    return (u16)(u >> 16);
}

// fp32 -> bf16, 4 elements/thread
__global__ __launch_bounds__(256)
void cvt_bf16(const float4* __restrict__ in, u16* __restrict__ out) {
    int i = blockIdx.x * 256 + threadIdx.x;
    float4 v = in[i];
    U16x4 o{f2bf(v.x), f2bf(v.y), f2bf(v.z), f2bf(v.w)};
    *(U16x4*)&out[(size_t)i * 4] = o;
}

// Weights -> one bf16 region: [Wv 65536][Woff 65536][Wa 32768][Wo 65536]
// (Woff++Wa contiguous = the 384-row fused B). Also bcat = boff++ba (384).
__global__ __launch_bounds__(256)
void prep_weights(const float* __restrict__ Wv, const float* __restrict__ Woff,
                  const float* __restrict__ Wa, const float* __restrict__ Wo,
                  const float* __restrict__ boff, const float* __restrict__ ba,
                  u16* __restrict__ dst, float* __restrict__ biascat) {
    int i = blockIdx.x * 256 + threadIdx.x;
    float v;
    if      (i <  65536) v = Wv[i];
    else if (i < 131072) v = Woff[i - 65536];
    else if (i < 163840) v = Wa[i - 131072];
    else                 v = Wo[i - 163840];
    dst[i] = f2bf(v);
    if (blockIdx.x == 0) {
        int t = threadIdx.x;
        biascat[t] = boff[t];
        if (t < 128) biascat[256 + t] = ba[t];
    }
}

// Persistent-B skinny-K GEMM: C[r][c] = sum_k A[r][k]*B[c][k] + bias[c].
// K=256, A bf16. Block = 4 waves, 128x128 tile. B-slab (128 cols x 256 k,
// 64 KB) staged into LDS ONCE with XOR chunk swizzle (conflict-free frag
// reads, verified R6); wave's 64-row A strip fully in registers; single
// barrier; 128 MFMAs. SPLIT: cols >= 256 -> C1 (ld 128) for fused off|logit.
template<bool SPLIT>
__global__ __launch_bounds__(256, 2)
void gemm_persist(const u16* __restrict__ A, const u16* __restrict__ B,
                  const float* __restrict__ bias, float* __restrict__ C0,
                  float* __restrict__ C1, int M) {
    __shared__ u16 Bs[128 * 256];      // 64 KB, [c][chunk-swizzled k]
    const int tid  = threadIdx.x;
    const int wave = tid >> 6;
    const int lane = tid & 63;
    const int ln16 = lane & 15;
    const int kq   = lane >> 4;            // 0..3
    const int col0 = blockIdx.x * 128;
    const int row0 = blockIdx.y * 128;
    const int wr   = (wave >> 1) * 64;
    const int wc   = (wave & 1) * 64;

    // stage B slab: 4096 16B chunks, coalesced; chunk index XOR-swizzled
    #pragma unroll
    for (int it = 0; it < 16; ++it) {
        int g  = it * 256 + tid;
        int c  = g >> 5;                   // slab col
        int ch = g & 31;                   // 16B chunk in row
        float4 v = *(const float4*)(B + (size_t)(col0 + c) * 256 + ch * 8);
        *(float4*)&Bs[c * 256 + (ch ^ (c & 7)) * 8] = v;
    }

    // A strip: 4 row-tiles x full K in registers (bf16, dwordx4 loads)
    bf16x8 a[4][8];
    #pragma unroll
    for (int i = 0; i < 4; ++i) {
        int gr = min(row0 + wr + i * 16 + ln16, M - 1);
        const u16* Ap = A + (size_t)gr * 256 + kq * 8;
        #pragma unroll
        for (int kt = 0; kt < 8; ++kt)
            a[i][kt] = *(const bf16x8*)(Ap + kt * 32);
    }
    __syncthreads();

    f32x4 acc[4][4] = {};
    #pragma unroll
    for (int kt = 0; kt < 8; ++kt) {
        bf16x8 b[4];
        #pragma unroll
        for (int j = 0; j < 4; ++j) {
            int c2 = wc + j * 16 + ln16;
            b[j] = *(const bf16x8*)&Bs[c2 * 256 + ((kt * 4 + kq) ^ (c2 & 7)) * 8];
        }
        #pragma unroll
        for (int i = 0; i < 4; ++i)
            #pragma unroll
            for (int j = 0; j < 4; ++j)
                acc[i][j] = __builtin_amdgcn_mfma_f32_16x16x32_bf16(
                    a[i][kt], b[j], acc[i][j], 0, 0, 0);
    }

    // C/D layout: col = lane&15, row = kq*4 + reg
    #pragma unroll
    for (int j = 0; j < 4; ++j) {
        int gc = col0 + wc + j * 16 + ln16;
        float bj = bias[gc];
        #pragma unroll
        for (int i = 0; i < 4; ++i) {
            int gr0 = row0 + wr + i * 16 + kq * 4;
            #pragma unroll
            for (int r = 0; r < 4; ++r) {
                int gr = gr0 + r;
                if (gr < M) {
                    if (SPLIT && gc >= 256)
                        C1[(size_t)gr * 128 + (gc - 256)] = acc[i][j][r] + bj;
                    else
                        C0[(size_t)gr * 256 + gc] = acc[i][j][r] + bj;
                }
            }
        }
    }
}

// Sampler: 4 queries per block. Phase A: 32 threads do the 32 (q,m) softmaxes.
// Phase B: 512 point-jobs (q,m,l,p) computed ONCE each -> LDS descriptors
// (4 clamped absolute value-row indices + 4 validity/attn-folded weights).
// Phase C: (q,m,e) lanes gather float4 channels using LDS descriptors.
__global__ __launch_bounds__(256)
void msda_sample(const float* __restrict__ value,    // (NB*LQ, 256) fp32
                 const float* __restrict__ refpts,   // (NB*LQ, 4, 2)
                 const float* __restrict__ off,      // (NB*LQ, 256) fp32
                 const float* __restrict__ logits,   // (NB*LQ, 128) fp32
                 u16* __restrict__ tmp) {            // (NB*LQ, 256) bf16
    __shared__ float sAw[4][8][16];
    __shared__ int   sLin[4][8][17][4];   // [17] pad: conflict-free m-groups
    __shared__ float sW[4][8][17][4];

    const int t  = threadIdx.x;
    const int qb = blockIdx.x * 4;

    // ---- Phase A: softmax per (q,m) ----
    if (t < 32) {
        const int qi = t >> 3, m = t & 7;
        const float* lg = logits + (size_t)(qb + qi) * 128 + m * 16;
        float e[16];
        float mx = -1e30f;
        #pragma unroll
        for (int i = 0; i < 16; ++i) { e[i] = lg[i]; mx = fmaxf(mx, e[i]); }
        float s = 0.f;
        #pragma unroll
        for (int i = 0; i < 16; ++i) { e[i] = __expf(e[i] - mx); s += e[i]; }
        const float inv = 1.f / s;
        #pragma unroll
        for (int i = 0; i < 16; ++i) sAw[qi][m][i] = e[i] * inv;
    }
    __syncthreads();

    // ---- Phase B: 512 point jobs, 2 per thread ----
    #pragma unroll
    for (int j2 = 0; j2 < 2; ++j2) {
        const int job = t + j2 * 256;
        const int qi = job >> 7;            // 128 jobs per query
        const int m  = (job >> 4) & 7;
        const int p  = job & 15;
        const int l  = p >> 2, pp = p & 3;
        const int q  = qb + qi;
        const int n  = (q >= LQ) ? 1 : 0;

        const int W = (l == 0) ? 100 : (l == 1) ? 50 : (l == 2) ? 25 : 13;
        const int H = W;
        const int st = (l == 0) ? 0 : (l == 1) ? 10000 : (l == 2) ? 12500 : 13125;

        const float rx = refpts[(size_t)q * 8 + l * 2 + 0];
        const float ry = refpts[(size_t)q * 8 + l * 2 + 1];
        const float ox = off[(size_t)q * 256 + m * 32 + (l * 4 + pp) * 2 + 0];
        const float oy = off[(size_t)q * 256 + m * 32 + (l * 4 + pp) * 2 + 1];

        // replicate reference arithmetic order
        const float locx = rx + ox / (float)W;
        const float locy = ry + oy / (float)H;
        const float grx = 2.f * locx - 1.f;
        const float gry = 2.f * locy - 1.f;
        const float gx = ((grx + 1.f) * (float)W - 1.f) * 0.5f;
        const float gy = ((gry + 1.f) * (float)H - 1.f) * 0.5f;
        const float x0f = floorf(gx), y0f = floorf(gy);
        const float fx = gx - x0f, fy = gy - y0f;
        const int x0 = (int)x0f, y0 = (int)y0f;
        const int x1 = x0 + 1, y1 = y0 + 1;

        const int cx0 = min(max(x0, 0), W - 1);
        const int cx1 = min(max(x1, 0), W - 1);
        const int cy0 = min(max(y0, 0), H - 1);
        const int cy1 = min(max(y1, 0), H - 1);
        const bool vx0 = (x0 >= 0) & (x0 < W);
        const bool vx1 = (x1 >= 0) & (x1 < W);
        const bool vy0 = (y0 >= 0) & (y0 < H);
        const bool vy1 = (y1 >= 0) & (y1 < H);

        const float aw = sAw[qi][m][p];
        const int base = n * LQ + st;
        sLin[qi][m][p][0] = base + cy0 * W + cx0;
        sLin[qi][m][p][1] = base + cy0 * W + cx1;
        sLin[qi][m][p][2] = base + cy1 * W + cx0;
        sLin[qi][m][p][3] = base + cy1 * W + cx1;
        sW[qi][m][p][0] = (vy0 & vx0) ? aw * (1.f - fy) * (1.f - fx) : 0.f;
        sW[qi][m][p][1] = (vy0 & vx1) ? aw * (1.f - fy) * fx         : 0.f;
        sW[qi][m][p][2] = (vy1 & vx0) ? aw * fy * (1.f - fx)         : 0.f;
        sW[qi][m][p][3] = (vy1 & vx1) ? aw * fy * fx                 : 0.f;
    }
    __syncthreads();

    // ---- Phase C: gather ----
    const int qi = t >> 6;
    const int m  = (t >> 3) & 7;
    const int e  = t & 7;
    const int q  = qb + qi;
    const float* vch = value + m * 32 + e * 4;

    float ax = 0.f, ay = 0.f, az = 0.f, aw_ = 0.f;
    #pragma unroll
    for (int p = 0; p < 16; ++p) {
        int4   L  = *(const int4*)&sLin[qi][m][p][0];
        float4 Wt = *(const float4*)&sW[qi][m][p][0];
        float4 c00 = *(const float4*)(vch + (size_t)L.x * 256);
        float4 c01 = *(const float4*)(vch + (size_t)L.y * 256);
        float4 c10 = *(const float4*)(vch + (size_t)L.z * 256);
        float4 c11 = *(const float4*)(vch + (size_t)L.w * 256);
        ax  += Wt.x * c00.x + Wt.y * c01.x + Wt.z * c10.x + Wt.w * c11.x;
        ay  += Wt.x * c00.y + Wt.y * c01.y + Wt.z * c10.y + Wt.w * c11.y;
        az  += Wt.x * c00.z + Wt.y * c01.z + Wt.z * c10.z + Wt.w * c11.z;
        aw_ += Wt.x * c00.w + Wt.y * c01.w + Wt.z * c10.w + Wt.w * c11.w;
    }
    U16x4 o{f2bf(ax), f2bf(ay), f2bf(az), f2bf(aw_)};
    *(U16x4*)&tmp[(size_t)q * 256 + m * 32 + e * 4] = o;
}

extern "C" void kernel_launch(void* const* d_in, const int* in_sizes, int n_in,
                              void* d_out, int out_size, void* d_ws, size_t ws_size,
                              hipStream_t stream) {
    const float* query  = (const float*)d_in[0];
    const float* refpts = (const float*)d_in[1];
    const float* inflat = (const float*)d_in[2];
    const float* Wv   = (const float*)d_in[5];
    const float* bv   = (const float*)d_in[6];
    const float* Woff = (const float*)d_in[7];
    const float* boff = (const float*)d_in[8];
    const float* Wa   = (const float*)d_in[9];
    const float* ba   = (const float*)d_in[10];
    const float* Wo   = (const float*)d_in[11];
    const float* bo   = (const float*)d_in[12];
    float* out = (float*)d_out;

    // workspace layout (~82.1 MB); qb reused as tmp, ib reused as logit
    char* ws = (char*)d_ws;
    constexpr size_t SZ16 = (size_t)NROWS * 256 * 2;            // 13,613,056
    constexpr size_t SZ32 = (size_t)NROWS * 256 * 4;            // 27,226,112
    u16*   qb    = (u16*)(ws);                                  // bf16 query; later tmp
    u16*   ib    = (u16*)(ws + SZ16);                           // bf16 input; later logit
    float* value = (float*)(ws + 2 * SZ16);                     // fp32
    float* offb  = (float*)(ws + 2 * SZ16 + SZ32);              // fp32
    u16*   wb    = (u16*)(ws + 2 * SZ16 + 2 * SZ32);            // bf16 weights
    float* bcat  = (float*)(ws + 2 * SZ16 + 2 * SZ32 + 229376 * 2);
    float* logit = (float*)ib;                                  // fp32 NROWS*128
    u16*   tmp   = qb;                                          // bf16 NROWS*256

    dim3 blk(256);
    hipLaunchKernelGGL(cvt_bf16, dim3(6647), blk, 0, stream, (const float4*)query,  qb);
    hipLaunchKernelGGL(cvt_bf16, dim3(6647), blk, 0, stream, (const float4*)inflat, ib);
    hipLaunchKernelGGL(prep_weights, dim3(896), blk, 0, stream,
                       Wv, Woff, Wa, Wo, boff, ba, wb, bcat);

    // value = inflat @ Wv^T + bv
    gemm_persist<false><<<dim3(2, 208), blk, 0, stream>>>(
        ib, wb, bv, value, nullptr, NROWS);
    // [offb | logit] = query @ [Woff;Wa]^T + [boff;ba]
    gemm_persist<true><<<dim3(3, 208), blk, 0, stream>>>(
        qb, wb + 65536, bcat, offb, logit, NROWS);

    hipLaunchKernelGGL(msda_sample, dim3(NROWS / 4), blk, 0, stream,
                       value, refpts, offb, logit, tmp);

    // out = tmp @ Wo^T + bo
    gemm_persist<false><<<dim3(2, 208), blk, 0, stream>>>(
        tmp, wb + 163840, bo, out, nullptr, NROWS);
}

// Round 8
// 249.058 us; speedup vs baseline: 1.2482x; 1.0730x over previous
//
#include <hip/hip_runtime.h>
#include <math.h>

// Problem constants (compile-time fixed)
#define NB   2
#define LQ   13294
#define NROWS (NB*LQ)      // 26588
#define CDIM 256

typedef unsigned short u16;
typedef unsigned int   u32;
typedef short bf16x8 __attribute__((ext_vector_type(8)));
typedef float f32x4  __attribute__((ext_vector_type(4)));

struct alignas(8) U16x4 { u16 x, y, z, w; };

__device__ __forceinline__ u16 f2bf(float f) {   // round-to-nearest-even
    u32 u = __builtin_bit_cast(u32, f);
    u += 0x7FFFu + ((u >> 16) & 1u);
    return (u16)(u >> 16);
}
__device__ __forceinline__ float bf2f(u16 h) {
    u32 u = ((u32)h) << 16;
    return __builtin_bit_cast(float, u);
}

// ONE prep dispatch: cvt query (blocks 0..6646), cvt inflat (6647..13293),
// weights+bias concat (13294..14189).
__global__ __launch_bounds__(256)
void prep_all(const float4* __restrict__ query, const float4* __restrict__ inflat,
              const float* __restrict__ Wv, const float* __restrict__ Woff,
              const float* __restrict__ Wa, const float* __restrict__ Wo,
              const float* __restrict__ boff, const float* __restrict__ ba,
              u16* __restrict__ qb, u16* __restrict__ ib,
              u16* __restrict__ wb, float* __restrict__ biascat) {
    const int b = blockIdx.x;
    const int t = threadIdx.x;
    if (b < 6647) {
        int i = b * 256 + t;
        float4 v = query[i];
        U16x4 o{f2bf(v.x), f2bf(v.y), f2bf(v.z), f2bf(v.w)};
        *(U16x4*)&qb[(size_t)i * 4] = o;
    } else if (b < 13294) {
        int i = (b - 6647) * 256 + t;
        float4 v = inflat[i];
        U16x4 o{f2bf(v.x), f2bf(v.y), f2bf(v.z), f2bf(v.w)};
        *(U16x4*)&ib[(size_t)i * 4] = o;
    } else {
        int i = (b - 13294) * 256 + t;
        float v;
        if      (i <  65536) v = Wv[i];
        else if (i < 131072) v = Woff[i - 65536];
        else if (i < 163840) v = Wa[i - 131072];
        else                 v = Wo[i - 163840];
        wb[i] = f2bf(v);
        if (b == 13294) {
            biascat[t] = boff[t];
            if (t < 128) biascat[256 + t] = ba[t];
        }
    }
}

// Persistent-B skinny-K GEMM core (K=256, A bf16, 128x128 tile, B slab in
// LDS once with XOR swizzle, A strip in registers, single barrier).
// Computes acc[4][4] for this block; caller-selected epilogue.
#define GEMM_CORE(A_, B_)                                                     \
    __shared__ u16 Bs[128 * 256];                                             \
    const int tid  = threadIdx.x;                                             \
    const int wave = tid >> 6;                                                \
    const int lane = tid & 63;                                                \
    const int ln16 = lane & 15;                                               \
    const int kq   = lane >> 4;                                               \
    const int row0 = blockIdx.y * 128;                                        \
    const int wr   = (wave >> 1) * 64;                                        \
    const int wc   = (wave & 1) * 64;                                         \
    _Pragma("unroll")                                                         \
    for (int it = 0; it < 16; ++it) {                                         \
        int g  = it * 256 + tid;                                              \
        int c  = g >> 5;                                                      \
        int ch = g & 31;                                                      \
        float4 v = *(const float4*)((B_) + (size_t)c * 256 + ch * 8);         \
        *(float4*)&Bs[c * 256 + (ch ^ (c & 7)) * 8] = v;                      \
    }                                                                         \
    bf16x8 a[4][8];                                                           \
    _Pragma("unroll")                                                         \
    for (int i = 0; i < 4; ++i) {                                             \
        int gr = min(row0 + wr + i * 16 + ln16, M - 1);                       \
        const u16* Ap = (A_) + (size_t)gr * 256 + kq * 8;                     \
        _Pragma("unroll")                                                     \
        for (int kt = 0; kt < 8; ++kt)                                        \
            a[i][kt] = *(const bf16x8*)(Ap + kt * 32);                        \
    }                                                                         \
    __syncthreads();                                                          \
    f32x4 acc[4][4] = {};                                                     \
    _Pragma("unroll")                                                         \
    for (int kt = 0; kt < 8; ++kt) {                                          \
        bf16x8 bfr[4];                                                        \
        _Pragma("unroll")                                                     \
        for (int j = 0; j < 4; ++j) {                                         \
            int c2 = wc + j * 16 + ln16;                                      \
            bfr[j] = *(const bf16x8*)&Bs[c2 * 256 + ((kt * 4 + kq) ^ (c2 & 7)) * 8]; \
        }                                                                     \
        _Pragma("unroll")                                                     \
        for (int i = 0; i < 4; ++i)                                           \
            _Pragma("unroll")                                                 \
            for (int j = 0; j < 4; ++j)                                       \
                acc[i][j] = __builtin_amdgcn_mfma_f32_16x16x32_bf16(          \
                    a[i][kt], bfr[j], acc[i][j], 0, 0, 0);                    \
    }

// Front GEMMs in ONE dispatch. blockIdx.x: 0,1 -> value = ib@Wv^T+bv (bf16
// out, ld 256); 2,3 -> offb cols (x-2)*128 = qb@Woff^T+boff (fp32, ld 256);
// 4 -> logit = qb@Wa^T+ba (fp32, ld 128).
__global__ __launch_bounds__(256, 2)
void gemm_front(const u16* __restrict__ qb, const u16* __restrict__ ib,
                const u16* __restrict__ wb, const float* __restrict__ bv,
                const float* __restrict__ bcat, u16* __restrict__ value,
                float* __restrict__ offb, float* __restrict__ logit, int M) {
    const int bx = blockIdx.x;
    const u16* Aptr = (bx < 2) ? ib : qb;
    const u16* Bptr = (bx < 2) ? (wb + (size_t)bx * 128 * 256)
                               : (wb + 65536 + (size_t)(bx - 2) * 128 * 256);
    const float* bias = (bx < 2) ? (bv + bx * 128) : (bcat + (bx - 2) * 128);

    GEMM_CORE(Aptr, Bptr)

    // C/D layout: col = lane&15, row = kq*4 + reg
    #pragma unroll
    for (int j = 0; j < 4; ++j) {
        int lc = wc + j * 16 + ln16;       // 0..127 within slab
        float bj = bias[lc];
        #pragma unroll
        for (int i = 0; i < 4; ++i) {
            int gr0 = row0 + wr + i * 16 + kq * 4;
            #pragma unroll
            for (int r = 0; r < 4; ++r) {
                int gr = gr0 + r;
                if (gr < M) {
                    float o = acc[i][j][r] + bj;
                    if (bx < 2)
                        value[(size_t)gr * 256 + bx * 128 + lc] = f2bf(o);
                    else if (bx < 4)
                        offb[(size_t)gr * 256 + (bx - 2) * 128 + lc] = o;
                    else
                        logit[(size_t)gr * 128 + lc] = o;
                }
            }
        }
    }
}

// out = tmp @ Wo^T + bo (fp32 out, ld 256)
__global__ __launch_bounds__(256, 2)
void gemm_out(const u16* __restrict__ A, const u16* __restrict__ Bw,
              const float* __restrict__ bias, float* __restrict__ C, int M) {
    const u16* Bptr = Bw + (size_t)blockIdx.x * 128 * 256;
    GEMM_CORE(A, Bptr)
    #pragma unroll
    for (int j = 0; j < 4; ++j) {
        int gc = blockIdx.x * 128 + wc + j * 16 + ln16;
        float bj = bias[gc];
        #pragma unroll
        for (int i = 0; i < 4; ++i) {
            int gr0 = row0 + wr + i * 16 + kq * 4;
            #pragma unroll
            for (int r = 0; r < 4; ++r) {
                int gr = gr0 + r;
                if (gr < M) C[(size_t)gr * 256 + gc] = acc[i][j][r] + bj;
            }
        }
    }
}

// Sampler: 4 queries/block, 3 phases (softmax / 512 point-descriptors /
// gather). value is bf16 (halved working set + gather bytes).
__global__ __launch_bounds__(256)
void msda_sample(const u16* __restrict__ value,     // (NB*LQ, 256) bf16
                 const float* __restrict__ refpts,  // (NB*LQ, 4, 2)
                 const float* __restrict__ off,     // (NB*LQ, 256) fp32
                 const float* __restrict__ logits,  // (NB*LQ, 128) fp32
                 u16* __restrict__ tmp) {           // (NB*LQ, 256) bf16
    __shared__ float sAw[4][8][16];
    __shared__ int   sLin[4][8][17][4];
    __shared__ float sW[4][8][17][4];

    const int t  = threadIdx.x;
    const int qb = blockIdx.x * 4;

    // ---- Phase A: softmax per (q,m) ----
    if (t < 32) {
        const int qi = t >> 3, m = t & 7;
        const float* lg = logits + (size_t)(qb + qi) * 128 + m * 16;
        float e[16];
        float mx = -1e30f;
        #pragma unroll
        for (int i = 0; i < 16; ++i) { e[i] = lg[i]; mx = fmaxf(mx, e[i]); }
        float s = 0.f;
        #pragma unroll
        for (int i = 0; i < 16; ++i) { e[i] = __expf(e[i] - mx); s += e[i]; }
        const float inv = 1.f / s;
        #pragma unroll
        for (int i = 0; i < 16; ++i) sAw[qi][m][i] = e[i] * inv;
    }
    __syncthreads();

    // ---- Phase B: 512 point jobs, 2 per thread ----
    #pragma unroll
    for (int j2 = 0; j2 < 2; ++j2) {
        const int job = t + j2 * 256;
        const int qi = job >> 7;
        const int m  = (job >> 4) & 7;
        const int p  = job & 15;
        const int l  = p >> 2, pp = p & 3;
        const int q  = qb + qi;
        const int n  = (q >= LQ) ? 1 : 0;

        const int W = (l == 0) ? 100 : (l == 1) ? 50 : (l == 2) ? 25 : 13;
        const int H = W;
        const int st = (l == 0) ? 0 : (l == 1) ? 10000 : (l == 2) ? 12500 : 13125;

        const float rx = refpts[(size_t)q * 8 + l * 2 + 0];
        const float ry = refpts[(size_t)q * 8 + l * 2 + 1];
        const float ox = off[(size_t)q * 256 + m * 32 + (l * 4 + pp) * 2 + 0];
        const float oy = off[(size_t)q * 256 + m * 32 + (l * 4 + pp) * 2 + 1];

        // replicate reference arithmetic order
        const float locx = rx + ox / (float)W;
        const float locy = ry + oy / (float)H;
        const float grx = 2.f * locx - 1.f;
        const float gry = 2.f * locy - 1.f;
        const float gx = ((grx + 1.f) * (float)W - 1.f) * 0.5f;
        const float gy = ((gry + 1.f) * (float)H - 1.f) * 0.5f;
        const float x0f = floorf(gx), y0f = floorf(gy);
        const float fx = gx - x0f, fy = gy - y0f;
        const int x0 = (int)x0f, y0 = (int)y0f;
        const int x1 = x0 + 1, y1 = y0 + 1;

        const int cx0 = min(max(x0, 0), W - 1);
        const int cx1 = min(max(x1, 0), W - 1);
        const int cy0 = min(max(y0, 0), H - 1);
        const int cy1 = min(max(y1, 0), H - 1);
        const bool vx0 = (x0 >= 0) & (x0 < W);
        const bool vx1 = (x1 >= 0) & (x1 < W);
        const bool vy0 = (y0 >= 0) & (y0 < H);
        const bool vy1 = (y1 >= 0) & (y1 < H);

        const float aw = sAw[qi][m][p];
        const int base = n * LQ + st;
        sLin[qi][m][p][0] = base + cy0 * W + cx0;
        sLin[qi][m][p][1] = base + cy0 * W + cx1;
        sLin[qi][m][p][2] = base + cy1 * W + cx0;
        sLin[qi][m][p][3] = base + cy1 * W + cx1;
        sW[qi][m][p][0] = (vy0 & vx0) ? aw * (1.f - fy) * (1.f - fx) : 0.f;
        sW[qi][m][p][1] = (vy0 & vx1) ? aw * (1.f - fy) * fx         : 0.f;
        sW[qi][m][p][2] = (vy1 & vx0) ? aw * fy * (1.f - fx)         : 0.f;
        sW[qi][m][p][3] = (vy1 & vx1) ? aw * fy * fx                 : 0.f;
    }
    __syncthreads();

    // ---- Phase C: gather (batched 4 points = 16 loads in flight) ----
    const int qi = t >> 6;
    const int m  = (t >> 3) & 7;
    const int e  = t & 7;
    const int q  = qb + qi;
    const u16* vch = value + m * 32 + e * 4;

    float ax = 0.f, ay = 0.f, az = 0.f, aw_ = 0.f;
    #pragma unroll
    for (int g = 0; g < 4; ++g) {
        U16x4 raw[16];
        float4 Wt4[4];
        #pragma unroll
        for (int pp = 0; pp < 4; ++pp) {
            int p = g * 4 + pp;
            int4 L = *(const int4*)&sLin[qi][m][p][0];
            Wt4[pp] = *(const float4*)&sW[qi][m][p][0];
            raw[pp * 4 + 0] = *(const U16x4*)(vch + (size_t)L.x * 256);
            raw[pp * 4 + 1] = *(const U16x4*)(vch + (size_t)L.y * 256);
            raw[pp * 4 + 2] = *(const U16x4*)(vch + (size_t)L.z * 256);
            raw[pp * 4 + 3] = *(const U16x4*)(vch + (size_t)L.w * 256);
        }
        #pragma unroll
        for (int pp = 0; pp < 4; ++pp) {
            const float* wp = (const float*)&Wt4[pp];
            #pragma unroll
            for (int c = 0; c < 4; ++c) {
                U16x4 r = raw[pp * 4 + c];
                float wgt = wp[c];
                ax  += wgt * bf2f(r.x);
                ay  += wgt * bf2f(r.y);
                az  += wgt * bf2f(r.z);
                aw_ += wgt * bf2f(r.w);
            }
        }
    }
    U16x4 o{f2bf(ax), f2bf(ay), f2bf(az), f2bf(aw_)};
    *(U16x4*)&tmp[(size_t)q * 256 + m * 32 + e * 4] = o;
}

extern "C" void kernel_launch(void* const* d_in, const int* in_sizes, int n_in,
                              void* d_out, int out_size, void* d_ws, size_t ws_size,
                              hipStream_t stream) {
    const float* query  = (const float*)d_in[0];
    const float* refpts = (const float*)d_in[1];
    const float* inflat = (const float*)d_in[2];
    const float* Wv   = (const float*)d_in[5];
    const float* bv   = (const float*)d_in[6];
    const float* Woff = (const float*)d_in[7];
    const float* boff = (const float*)d_in[8];
    const float* Wa   = (const float*)d_in[9];
    const float* ba   = (const float*)d_in[10];
    const float* Wo   = (const float*)d_in[11];
    const float* bo   = (const float*)d_in[12];
    float* out = (float*)d_out;

    // workspace layout (~82 MB)
    char* ws = (char*)d_ws;
    constexpr size_t SZ16 = (size_t)NROWS * 256 * 2;   // 13,613,056
    constexpr size_t SZ32 = (size_t)NROWS * 256 * 4;   // 27,226,112
    constexpr size_t SZL  = (size_t)NROWS * 128 * 4;   // 13,613,056
    u16*   qb    = (u16*)(ws);                         // bf16 query; later tmp
    u16*   ib    = (u16*)(ws + SZ16);                  // bf16 input
    u16*   value = (u16*)(ws + 2 * SZ16);              // bf16 value
    float* offb  = (float*)(ws + 3 * SZ16);            // fp32
    float* logit = (float*)(ws + 3 * SZ16 + SZ32);     // fp32
    u16*   wb    = (u16*)(ws + 3 * SZ16 + SZ32 + SZL); // bf16 weights
    float* bcat  = (float*)(ws + 3 * SZ16 + SZ32 + SZL + 229376 * 2);
    u16*   tmp   = qb;

    dim3 blk(256);
    hipLaunchKernelGGL(prep_all, dim3(14190), blk, 0, stream,
                       (const float4*)query, (const float4*)inflat,
                       Wv, Woff, Wa, Wo, boff, ba, qb, ib, wb, bcat);

    gemm_front<<<dim3(5, 208), blk, 0, stream>>>(
        qb, ib, wb, bv, bcat, value, offb, logit, NROWS);

    hipLaunchKernelGGL(msda_sample, dim3(NROWS / 4), blk, 0, stream,
                       value, refpts, offb, logit, tmp);

    gemm_out<<<dim3(2, 208), blk, 0, stream>>>(
        tmp, wb + 163840, bo, out, NROWS);
}

// Round 9
// 245.793 us; speedup vs baseline: 1.2648x; 1.0133x over previous
//
#include <hip/hip_runtime.h>
#include <math.h>

// Problem constants (compile-time fixed)
#define NB   2
#define LQ   13294
#define NROWS (NB*LQ)      // 26588
#define CDIM 256

typedef unsigned short u16;
typedef unsigned int   u32;
typedef short bf16x8 __attribute__((ext_vector_type(8)));
typedef float f32x4  __attribute__((ext_vector_type(4)));

struct alignas(8) U16x4 { u16 x, y, z, w; };

__device__ __forceinline__ u16 f2bf(float f) {   // round-to-nearest-even
    u32 u = __builtin_bit_cast(u32, f);
    u += 0x7FFFu + ((u >> 16) & 1u);
    return (u16)(u >> 16);
}
__device__ __forceinline__ float bf2f(u16 h) {
    u32 u = ((u32)h) << 16;
    return __builtin_bit_cast(float, u);
}

// ONE prep dispatch: cvt query (blocks 0..6646), cvt inflat (6647..13293),
// weights+bias concat (13294..14189).
__global__ __launch_bounds__(256)
void prep_all(const float4* __restrict__ query, const float4* __restrict__ inflat,
              const float* __restrict__ Wv, const float* __restrict__ Woff,
              const float* __restrict__ Wa, const float* __restrict__ Wo,
              const float* __restrict__ boff, const float* __restrict__ ba,
              u16* __restrict__ qb, u16* __restrict__ ib,
              u16* __restrict__ wb, float* __restrict__ biascat) {
    const int b = blockIdx.x;
    const int t = threadIdx.x;
    if (b < 6647) {
        int i = b * 256 + t;
        float4 v = query[i];
        U16x4 o{f2bf(v.x), f2bf(v.y), f2bf(v.z), f2bf(v.w)};
        *(U16x4*)&qb[(size_t)i * 4] = o;
    } else if (b < 13294) {
        int i = (b - 6647) * 256 + t;
        float4 v = inflat[i];
        U16x4 o{f2bf(v.x), f2bf(v.y), f2bf(v.z), f2bf(v.w)};
        *(U16x4*)&ib[(size_t)i * 4] = o;
    } else {
        int i = (b - 13294) * 256 + t;
        float v;
        if      (i <  65536) v = Wv[i];
        else if (i < 131072) v = Woff[i - 65536];
        else if (i < 163840) v = Wa[i - 131072];
        else                 v = Wo[i - 163840];
        wb[i] = f2bf(v);
        if (b == 13294) {
            biascat[t] = boff[t];
            if (t < 128) biascat[256 + t] = ba[t];
        }
    }
}

// B-stationary register GEMM: C[r][c] = sum_k A[r][k]*B[c][k] + bias[c].
// K=256, A/B bf16. ONE WAVE per block, NO LDS, NO barriers.
// Wave holds its 64-col B strip fully in registers (b[4][8], 128 VGPR) and
// streams 4 row-tiles of 16 rows (software-pipelined A-frag loads).
// Grid: (strips, ceil(M/64)). MODE 0: bf16 C0 ld 256 (value);
// MODE 1: fused — cols<256 -> fp32 C0 ld 256 (off), cols>=256 -> C1 ld 128
// (logit); MODE 2: fp32 C0 ld 256 (out).
template<int MODE>
__global__ __launch_bounds__(64, 2)
void gemm_breg(const u16* __restrict__ A, const u16* __restrict__ Bw,
               const float* __restrict__ bias, void* __restrict__ C0,
               float* __restrict__ C1, int M) {
    const int lane = threadIdx.x;
    const int ln16 = lane & 15;
    const int kq   = lane >> 4;            // 0..3
    const int col0 = blockIdx.x * 64;
    const int rt0  = blockIdx.y * 64;

    // B strip: 64 cols x 256 K in registers
    bf16x8 b[4][8];
    #pragma unroll
    for (int j = 0; j < 4; ++j) {
        const u16* Bp = Bw + (size_t)(col0 + j * 16 + ln16) * 256 + kq * 8;
        #pragma unroll
        for (int kt = 0; kt < 8; ++kt)
            b[j][kt] = *(const bf16x8*)(Bp + kt * 32);
    }
    float bs[4];
    #pragma unroll
    for (int j = 0; j < 4; ++j) bs[j] = bias[col0 + j * 16 + ln16];

    // software-pipelined A row-tiles (16 rows each)
    bf16x8 a[2][8];
    {
        int gr = min(rt0 + ln16, M - 1);
        const u16* Ap = A + (size_t)gr * 256 + kq * 8;
        #pragma unroll
        for (int kt = 0; kt < 8; ++kt) a[0][kt] = *(const bf16x8*)(Ap + kt * 32);
    }
    #pragma unroll
    for (int rt = 0; rt < 4; ++rt) {
        if (rt < 3) {
            int gr = min(rt0 + (rt + 1) * 16 + ln16, M - 1);
            const u16* Ap = A + (size_t)gr * 256 + kq * 8;
            #pragma unroll
            for (int kt = 0; kt < 8; ++kt)
                a[(rt + 1) & 1][kt] = *(const bf16x8*)(Ap + kt * 32);
        }
        f32x4 acc[4] = {};
        #pragma unroll
        for (int kt = 0; kt < 8; ++kt)
            #pragma unroll
            for (int j = 0; j < 4; ++j)
                acc[j] = __builtin_amdgcn_mfma_f32_16x16x32_bf16(
                    a[rt & 1][kt], b[j][kt], acc[j], 0, 0, 0);

        // C/D layout (session-verified): col = ln16 (B), row = kq*4 + reg (A)
        #pragma unroll
        for (int j = 0; j < 4; ++j) {
            int gc = col0 + j * 16 + ln16;
            #pragma unroll
            for (int r = 0; r < 4; ++r) {
                int gr = rt0 + rt * 16 + kq * 4 + r;
                if (gr < M) {
                    float o = acc[j][r] + bs[j];
                    if (MODE == 0)
                        ((u16*)C0)[(size_t)gr * 256 + gc] = f2bf(o);
                    else if (MODE == 2)
                        ((float*)C0)[(size_t)gr * 256 + gc] = o;
                    else {
                        if (gc < 256) ((float*)C0)[(size_t)gr * 256 + gc] = o;
                        else          C1[(size_t)gr * 128 + (gc - 256)] = o;
                    }
                }
            }
        }
    }
}

// Sampler: 4 queries/block, 3 phases (softmax / 512 point-descriptors /
// gather). value is bf16 (halved working set + gather bytes).
__global__ __launch_bounds__(256)
void msda_sample(const u16* __restrict__ value,     // (NB*LQ, 256) bf16
                 const float* __restrict__ refpts,  // (NB*LQ, 4, 2)
                 const float* __restrict__ off,     // (NB*LQ, 256) fp32
                 const float* __restrict__ logits,  // (NB*LQ, 128) fp32
                 u16* __restrict__ tmp) {           // (NB*LQ, 256) bf16
    __shared__ float sAw[4][8][16];
    __shared__ int   sLin[4][8][17][4];
    __shared__ float sW[4][8][17][4];

    const int t  = threadIdx.x;
    const int qb = blockIdx.x * 4;

    // ---- Phase A: softmax per (q,m) ----
    if (t < 32) {
        const int qi = t >> 3, m = t & 7;
        const float* lg = logits + (size_t)(qb + qi) * 128 + m * 16;
        float e[16];
        float mx = -1e30f;
        #pragma unroll
        for (int i = 0; i < 16; ++i) { e[i] = lg[i]; mx = fmaxf(mx, e[i]); }
        float s = 0.f;
        #pragma unroll
        for (int i = 0; i < 16; ++i) { e[i] = __expf(e[i] - mx); s += e[i]; }
        const float inv = 1.f / s;
        #pragma unroll
        for (int i = 0; i < 16; ++i) sAw[qi][m][i] = e[i] * inv;
    }
    __syncthreads();

    // ---- Phase B: 512 point jobs, 2 per thread ----
    #pragma unroll
    for (int j2 = 0; j2 < 2; ++j2) {
        const int job = t + j2 * 256;
        const int qi = job >> 7;
        const int m  = (job >> 4) & 7;
        const int p  = job & 15;
        const int l  = p >> 2, pp = p & 3;
        const int q  = qb + qi;
        const int n  = (q >= LQ) ? 1 : 0;

        const int W = (l == 0) ? 100 : (l == 1) ? 50 : (l == 2) ? 25 : 13;
        const int H = W;
        const int st = (l == 0) ? 0 : (l == 1) ? 10000 : (l == 2) ? 12500 : 13125;

        const float rx = refpts[(size_t)q * 8 + l * 2 + 0];
        const float ry = refpts[(size_t)q * 8 + l * 2 + 1];
        const float ox = off[(size_t)q * 256 + m * 32 + (l * 4 + pp) * 2 + 0];
        const float oy = off[(size_t)q * 256 + m * 32 + (l * 4 + pp) * 2 + 1];

        // replicate reference arithmetic order
        const float locx = rx + ox / (float)W;
        const float locy = ry + oy / (float)H;
        const float grx = 2.f * locx - 1.f;
        const float gry = 2.f * locy - 1.f;
        const float gx = ((grx + 1.f) * (float)W - 1.f) * 0.5f;
        const float gy = ((gry + 1.f) * (float)H - 1.f) * 0.5f;
        const float x0f = floorf(gx), y0f = floorf(gy);
        const float fx = gx - x0f, fy = gy - y0f;
        const int x0 = (int)x0f, y0 = (int)y0f;
        const int x1 = x0 + 1, y1 = y0 + 1;

        const int cx0 = min(max(x0, 0), W - 1);
        const int cx1 = min(max(x1, 0), W - 1);
        const int cy0 = min(max(y0, 0), H - 1);
        const int cy1 = min(max(y1, 0), H - 1);
        const bool vx0 = (x0 >= 0) & (x0 < W);
        const bool vx1 = (x1 >= 0) & (x1 < W);
        const bool vy0 = (y0 >= 0) & (y0 < H);
        const bool vy1 = (y1 >= 0) & (y1 < H);

        const float aw = sAw[qi][m][p];
        const int base = n * LQ + st;
        sLin[qi][m][p][0] = base + cy0 * W + cx0;
        sLin[qi][m][p][1] = base + cy0 * W + cx1;
        sLin[qi][m][p][2] = base + cy1 * W + cx0;
        sLin[qi][m][p][3] = base + cy1 * W + cx1;
        sW[qi][m][p][0] = (vy0 & vx0) ? aw * (1.f - fy) * (1.f - fx) : 0.f;
        sW[qi][m][p][1] = (vy0 & vx1) ? aw * (1.f - fy) * fx         : 0.f;
        sW[qi][m][p][2] = (vy1 & vx0) ? aw * fy * (1.f - fx)         : 0.f;
        sW[qi][m][p][3] = (vy1 & vx1) ? aw * fy * fx                 : 0.f;
    }
    __syncthreads();

    // ---- Phase C: gather (batched 4 points = 16 loads in flight) ----
    const int qi = t >> 6;
    const int m  = (t >> 3) & 7;
    const int e  = t & 7;
    const int q  = qb + qi;
    const u16* vch = value + m * 32 + e * 4;

    float ax = 0.f, ay = 0.f, az = 0.f, aw_ = 0.f;
    #pragma unroll
    for (int g = 0; g < 4; ++g) {
        U16x4 raw[16];
        float4 Wt4[4];
        #pragma unroll
        for (int pp = 0; pp < 4; ++pp) {
            int p = g * 4 + pp;
            int4 L = *(const int4*)&sLin[qi][m][p][0];
            Wt4[pp] = *(const float4*)&sW[qi][m][p][0];
            raw[pp * 4 + 0] = *(const U16x4*)(vch + (size_t)L.x * 256);
            raw[pp * 4 + 1] = *(const U16x4*)(vch + (size_t)L.y * 256);
            raw[pp * 4 + 2] = *(const U16x4*)(vch + (size_t)L.z * 256);
            raw[pp * 4 + 3] = *(const U16x4*)(vch + (size_t)L.w * 256);
        }
        #pragma unroll
        for (int pp = 0; pp < 4; ++pp) {
            const float* wp = (const float*)&Wt4[pp];
            #pragma unroll
            for (int c = 0; c < 4; ++c) {
                U16x4 r = raw[pp * 4 + c];
                float wgt = wp[c];
                ax  += wgt * bf2f(r.x);
                ay  += wgt * bf2f(r.y);
                az  += wgt * bf2f(r.z);
                aw_ += wgt * bf2f(r.w);
            }
        }
    }
    U16x4 o{f2bf(ax), f2bf(ay), f2bf(az), f2bf(aw_)};
    *(U16x4*)&tmp[(size_t)q * 256 + m * 32 + e * 4] = o;
}

extern "C" void kernel_launch(void* const* d_in, const int* in_sizes, int n_in,
                              void* d_out, int out_size, void* d_ws, size_t ws_size,
                              hipStream_t stream) {
    const float* query  = (const float*)d_in[0];
    const float* refpts = (const float*)d_in[1];
    const float* inflat = (const float*)d_in[2];
    const float* Wv   = (const float*)d_in[5];
    const float* bv   = (const float*)d_in[6];
    const float* Woff = (const float*)d_in[7];
    const float* boff = (const float*)d_in[8];
    const float* Wa   = (const float*)d_in[9];
    const float* ba   = (const float*)d_in[10];
    const float* Wo   = (const float*)d_in[11];
    const float* bo   = (const float*)d_in[12];
    float* out = (float*)d_out;

    // workspace layout (~82 MB)
    char* ws = (char*)d_ws;
    constexpr size_t SZ16 = (size_t)NROWS * 256 * 2;   // 13,613,056
    constexpr size_t SZ32 = (size_t)NROWS * 256 * 4;   // 27,226,112
    constexpr size_t SZL  = (size_t)NROWS * 128 * 4;   // 13,613,056
    u16*   qb    = (u16*)(ws);                         // bf16 query; later tmp
    u16*   ib    = (u16*)(ws + SZ16);                  // bf16 input
    u16*   value = (u16*)(ws + 2 * SZ16);              // bf16 value
    float* offb  = (float*)(ws + 3 * SZ16);            // fp32
    float* logit = (float*)(ws + 3 * SZ16 + SZ32);     // fp32
    u16*   wb    = (u16*)(ws + 3 * SZ16 + SZ32 + SZL); // bf16 weights
    float* bcat  = (float*)(ws + 3 * SZ16 + SZ32 + SZL + 229376 * 2);
    u16*   tmp   = qb;

    const int RG = (NROWS + 63) / 64;   // 416 row-groups

    hipLaunchKernelGGL(prep_all, dim3(14190), dim3(256), 0, stream,
                       (const float4*)query, (const float4*)inflat,
                       Wv, Woff, Wa, Wo, boff, ba, qb, ib, wb, bcat);

    // value = inflat @ Wv^T + bv  (bf16 out)
    gemm_breg<0><<<dim3(4, RG), dim3(64), 0, stream>>>(
        ib, wb, bv, (void*)value, nullptr, NROWS);
    // [offb | logit] = query @ [Woff;Wa]^T + [boff;ba]
    gemm_breg<1><<<dim3(6, RG), dim3(64), 0, stream>>>(
        qb, wb + 65536, bcat, (void*)offb, logit, NROWS);

    hipLaunchKernelGGL(msda_sample, dim3(NROWS / 4), dim3(256), 0, stream,
                       value, refpts, offb, logit, tmp);

    // out = tmp @ Wo^T + bo  (fp32 out)
    gemm_breg<2><<<dim3(4, RG), dim3(64), 0, stream>>>(
        tmp, wb + 163840, bo, (void*)out, nullptr, NROWS);
}

// Round 10
// 228.817 us; speedup vs baseline: 1.3586x; 1.0742x over previous
//
#include <hip/hip_runtime.h>
#include <math.h>

// Problem constants (compile-time fixed)
#define NB   2
#define LQ   13294
#define NROWS (NB*LQ)      // 26588
#define CDIM 256

typedef unsigned short u16;
typedef unsigned int   u32;
typedef short bf16x8 __attribute__((ext_vector_type(8)));
typedef float f32x4  __attribute__((ext_vector_type(4)));

struct alignas(8) U16x4 { u16 x, y, z, w; };

__device__ __forceinline__ u16 f2bf(float f) {   // round-to-nearest-even
    u32 u = __builtin_bit_cast(u32, f);
    u += 0x7FFFu + ((u >> 16) & 1u);
    return (u16)(u >> 16);
}
__device__ __forceinline__ float bf2f(u16 h) {
    u32 u = ((u32)h) << 16;
    return __builtin_bit_cast(float, u);
}

// ONE prep dispatch: cvt query (blocks 0..6646), cvt inflat (6647..13293),
// weights+bias concat (13294..14189).
__global__ __launch_bounds__(256)
void prep_all(const float4* __restrict__ query, const float4* __restrict__ inflat,
              const float* __restrict__ Wv, const float* __restrict__ Woff,
              const float* __restrict__ Wa, const float* __restrict__ Wo,
              const float* __restrict__ boff, const float* __restrict__ ba,
              u16* __restrict__ qb, u16* __restrict__ ib,
              u16* __restrict__ wb, float* __restrict__ biascat) {
    const int b = blockIdx.x;
    const int t = threadIdx.x;
    if (b < 6647) {
        int i = b * 256 + t;
        float4 v = query[i];
        U16x4 o{f2bf(v.x), f2bf(v.y), f2bf(v.z), f2bf(v.w)};
        *(U16x4*)&qb[(size_t)i * 4] = o;
    } else if (b < 13294) {
        int i = (b - 6647) * 256 + t;
        float4 v = inflat[i];
        U16x4 o{f2bf(v.x), f2bf(v.y), f2bf(v.z), f2bf(v.w)};
        *(U16x4*)&ib[(size_t)i * 4] = o;
    } else {
        int i = (b - 13294) * 256 + t;
        float v;
        if      (i <  65536) v = Wv[i];
        else if (i < 131072) v = Woff[i - 65536];
        else if (i < 163840) v = Wa[i - 131072];
        else                 v = Wo[i - 163840];
        wb[i] = f2bf(v);
        if (b == 13294) {
            biascat[t] = boff[t];
            if (t < 128) biascat[256 + t] = ba[t];
        }
    }
}

// Occupancy-first GEMM core: 64x64 tile, BK=64, 4 K-iterations, 16 KB LDS
// (XOR-swizzled, 2-way max conflicts = free), tiny VGPR footprint.
// Wave w computes 32x32 quadrant at (w>>1, w&1).
__device__ __forceinline__ void gemm_core64(
    const u16* __restrict__ A, const u16* __restrict__ Bw, int M, int row0,
    u16* As, u16* Bs, f32x4 (&acc)[2][2]) {
    const int tid  = threadIdx.x;
    const int wave = tid >> 6;
    const int lane = tid & 63;
    const int ln16 = lane & 15;
    const int kq   = lane >> 4;
    const int wrow = (wave >> 1) * 32;
    const int wcol = (wave & 1) * 32;

    #pragma unroll
    for (int kt = 0; kt < 4; ++kt) {
        const int k0 = kt * 64;
        // stage A(64 rows x 64 k) + B(64 cols x 64 k): 2 16B chunks each/thread
        #pragma unroll
        for (int it = 0; it < 2; ++it) {
            int chunk = it * 256 + tid;       // 0..511
            int row = chunk >> 3;             // 0..63
            int ch  = chunk & 7;              // 16B chunk within 128B row
            int gra = min(row0 + row, M - 1);
            float4 va = *(const float4*)(A  + (size_t)gra * 256 + k0 + ch * 8);
            float4 vb = *(const float4*)(Bw + (size_t)row * 256 + k0 + ch * 8);
            *(float4*)&As[row * 64 + (ch ^ (row & 7)) * 8] = va;
            *(float4*)&Bs[row * 64 + (ch ^ (row & 7)) * 8] = vb;
        }
        __syncthreads();
        #pragma unroll
        for (int kf = 0; kf < 2; ++kf) {
            int ck = kf * 4 + kq;             // chunk index for k = kf*32+kq*8
            bf16x8 a[2], b[2];
            #pragma unroll
            for (int i = 0; i < 2; ++i) {
                int r = wrow + i * 16 + ln16;
                a[i] = *(const bf16x8*)&As[r * 64 + ((ck ^ (r & 7)) * 8)];
                int c = wcol + i * 16 + ln16;
                b[i] = *(const bf16x8*)&Bs[c * 64 + ((ck ^ (c & 7)) * 8)];
            }
            #pragma unroll
            for (int i = 0; i < 2; ++i)
                #pragma unroll
                for (int j = 0; j < 2; ++j)
                    acc[i][j] = __builtin_amdgcn_mfma_f32_16x16x32_bf16(
                        a[i], b[j], acc[i][j], 0, 0, 0);
        }
        __syncthreads();
    }
}

// Front GEMMs merged: strips 0..3 -> value = ib@Wv^T+bv (bf16, ld 256);
// strips 4..9 -> [offb | logit] = qb@[Woff;Wa]^T + bcat.
__global__ __launch_bounds__(256, 4)
void gemm_front(const u16* __restrict__ qb, const u16* __restrict__ ib,
                const u16* __restrict__ wb, const float* __restrict__ bv,
                const float* __restrict__ bcat, u16* __restrict__ value,
                float* __restrict__ offb, float* __restrict__ logit, int M) {
    __shared__ u16 As[64 * 64];
    __shared__ u16 Bs[64 * 64];
    const int s    = blockIdx.x;          // 0..9
    const int row0 = blockIdx.y * 64;
    const u16* A  = (s < 4) ? ib : qb;
    const u16* Bw = (s < 4) ? wb + (size_t)s * 64 * 256
                            : wb + 65536 + (size_t)(s - 4) * 64 * 256;
    const float* bias = (s < 4) ? bv + s * 64 : bcat + (s - 4) * 64;

    f32x4 acc[2][2] = {};
    gemm_core64(A, Bw, M, row0, As, Bs, acc);

    const int lane = threadIdx.x & 63;
    const int wave = threadIdx.x >> 6;
    const int ln16 = lane & 15, kq = lane >> 4;
    const int wrow = (wave >> 1) * 32, wcol = (wave & 1) * 32;
    #pragma unroll
    for (int j = 0; j < 2; ++j) {
        int lc = wcol + j * 16 + ln16;    // 0..63 within strip
        float bj = bias[lc];
        #pragma unroll
        for (int i = 0; i < 2; ++i) {
            #pragma unroll
            for (int r = 0; r < 4; ++r) {
                int gr = row0 + wrow + i * 16 + kq * 4 + r;
                if (gr < M) {
                    float o = acc[i][j][r] + bj;
                    if (s < 4)
                        value[(size_t)gr * 256 + s * 64 + lc] = f2bf(o);
                    else {
                        int gc = (s - 4) * 64 + lc;
                        if (gc < 256) offb[(size_t)gr * 256 + gc] = o;
                        else          logit[(size_t)gr * 128 + (gc - 256)] = o;
                    }
                }
            }
        }
    }
}

// out = tmp @ Wo^T + bo (fp32, ld 256), strips 0..3
__global__ __launch_bounds__(256, 4)
void gemm_out(const u16* __restrict__ A, const u16* __restrict__ Bw0,
              const float* __restrict__ bias, float* __restrict__ C, int M) {
    __shared__ u16 As[64 * 64];
    __shared__ u16 Bs[64 * 64];
    const int s    = blockIdx.x;
    const int row0 = blockIdx.y * 64;
    const u16* Bw = Bw0 + (size_t)s * 64 * 256;

    f32x4 acc[2][2] = {};
    gemm_core64(A, Bw, M, row0, As, Bs, acc);

    const int lane = threadIdx.x & 63;
    const int wave = threadIdx.x >> 6;
    const int ln16 = lane & 15, kq = lane >> 4;
    const int wrow = (wave >> 1) * 32, wcol = (wave & 1) * 32;
    #pragma unroll
    for (int j = 0; j < 2; ++j) {
        int gc = s * 64 + wcol + j * 16 + ln16;
        float bj = bias[gc];
        #pragma unroll
        for (int i = 0; i < 2; ++i) {
            #pragma unroll
            for (int r = 0; r < 4; ++r) {
                int gr = row0 + wrow + i * 16 + kq * 4 + r;
                if (gr < M) C[(size_t)gr * 256 + gc] = acc[i][j][r] + bj;
            }
        }
    }
}

// Sampler: 4 queries/block, 3 phases (softmax / 512 point-descriptors /
// gather). value is bf16 (halved working set + gather bytes).
__global__ __launch_bounds__(256)
void msda_sample(const u16* __restrict__ value,     // (NB*LQ, 256) bf16
                 const float* __restrict__ refpts,  // (NB*LQ, 4, 2)
                 const float* __restrict__ off,     // (NB*LQ, 256) fp32
                 const float* __restrict__ logits,  // (NB*LQ, 128) fp32
                 u16* __restrict__ tmp) {           // (NB*LQ, 256) bf16
    __shared__ float sAw[4][8][16];
    __shared__ int   sLin[4][8][17][4];
    __shared__ float sW[4][8][17][4];

    const int t  = threadIdx.x;
    const int qb = blockIdx.x * 4;

    // ---- Phase A: softmax per (q,m) ----
    if (t < 32) {
        const int qi = t >> 3, m = t & 7;
        const float* lg = logits + (size_t)(qb + qi) * 128 + m * 16;
        float e[16];
        float mx = -1e30f;
        #pragma unroll
        for (int i = 0; i < 16; ++i) { e[i] = lg[i]; mx = fmaxf(mx, e[i]); }
        float s = 0.f;
        #pragma unroll
        for (int i = 0; i < 16; ++i) { e[i] = __expf(e[i] - mx); s += e[i]; }
        const float inv = 1.f / s;
        #pragma unroll
        for (int i = 0; i < 16; ++i) sAw[qi][m][i] = e[i] * inv;
    }
    __syncthreads();

    // ---- Phase B: 512 point jobs, 2 per thread ----
    #pragma unroll
    for (int j2 = 0; j2 < 2; ++j2) {
        const int job = t + j2 * 256;
        const int qi = job >> 7;
        const int m  = (job >> 4) & 7;
        const int p  = job & 15;
        const int l  = p >> 2, pp = p & 3;
        const int q  = qb + qi;
        const int n  = (q >= LQ) ? 1 : 0;

        const int W = (l == 0) ? 100 : (l == 1) ? 50 : (l == 2) ? 25 : 13;
        const int H = W;
        const int st = (l == 0) ? 0 : (l == 1) ? 10000 : (l == 2) ? 12500 : 13125;

        const float rx = refpts[(size_t)q * 8 + l * 2 + 0];
        const float ry = refpts[(size_t)q * 8 + l * 2 + 1];
        const float ox = off[(size_t)q * 256 + m * 32 + (l * 4 + pp) * 2 + 0];
        const float oy = off[(size_t)q * 256 + m * 32 + (l * 4 + pp) * 2 + 1];

        // replicate reference arithmetic order
        const float locx = rx + ox / (float)W;
        const float locy = ry + oy / (float)H;
        const float grx = 2.f * locx - 1.f;
        const float gry = 2.f * locy - 1.f;
        const float gx = ((grx + 1.f) * (float)W - 1.f) * 0.5f;
        const float gy = ((gry + 1.f) * (float)H - 1.f) * 0.5f;
        const float x0f = floorf(gx), y0f = floorf(gy);
        const float fx = gx - x0f, fy = gy - y0f;
        const int x0 = (int)x0f, y0 = (int)y0f;
        const int x1 = x0 + 1, y1 = y0 + 1;

        const int cx0 = min(max(x0, 0), W - 1);
        const int cx1 = min(max(x1, 0), W - 1);
        const int cy0 = min(max(y0, 0), H - 1);
        const int cy1 = min(max(y1, 0), H - 1);
        const bool vx0 = (x0 >= 0) & (x0 < W);
        const bool vx1 = (x1 >= 0) & (x1 < W);
        const bool vy0 = (y0 >= 0) & (y0 < H);
        const bool vy1 = (y1 >= 0) & (y1 < H);

        const float aw = sAw[qi][m][p];
        const int base = n * LQ + st;
        sLin[qi][m][p][0] = base + cy0 * W + cx0;
        sLin[qi][m][p][1] = base + cy0 * W + cx1;
        sLin[qi][m][p][2] = base + cy1 * W + cx0;
        sLin[qi][m][p][3] = base + cy1 * W + cx1;
        sW[qi][m][p][0] = (vy0 & vx0) ? aw * (1.f - fy) * (1.f - fx) : 0.f;
        sW[qi][m][p][1] = (vy0 & vx1) ? aw * (1.f - fy) * fx         : 0.f;
        sW[qi][m][p][2] = (vy1 & vx0) ? aw * fy * (1.f - fx)         : 0.f;
        sW[qi][m][p][3] = (vy1 & vx1) ? aw * fy * fx                 : 0.f;
    }
    __syncthreads();

    // ---- Phase C: gather (batched 4 points = 16 loads in flight) ----
    const int qi = t >> 6;
    const int m  = (t >> 3) & 7;
    const int e  = t & 7;
    const int q  = qb + qi;
    const u16* vch = value + m * 32 + e * 4;

    float ax = 0.f, ay = 0.f, az = 0.f, aw_ = 0.f;
    #pragma unroll
    for (int g = 0; g < 4; ++g) {
        U16x4 raw[16];
        float4 Wt4[4];
        #pragma unroll
        for (int pp = 0; pp < 4; ++pp) {
            int p = g * 4 + pp;
            int4 L = *(const int4*)&sLin[qi][m][p][0];
            Wt4[pp] = *(const float4*)&sW[qi][m][p][0];
            raw[pp * 4 + 0] = *(const U16x4*)(vch + (size_t)L.x * 256);
            raw[pp * 4 + 1] = *(const U16x4*)(vch + (size_t)L.y * 256);
            raw[pp * 4 + 2] = *(const U16x4*)(vch + (size_t)L.z * 256);
            raw[pp * 4 + 3] = *(const U16x4*)(vch + (size_t)L.w * 256);
        }
        #pragma unroll
        for (int pp = 0; pp < 4; ++pp) {
            const float* wp = (const float*)&Wt4[pp];
            #pragma unroll
            for (int c = 0; c < 4; ++c) {
                U16x4 r = raw[pp * 4 + c];
                float wgt = wp[c];
                ax  += wgt * bf2f(r.x);
                ay  += wgt * bf2f(r.y);
                az  += wgt * bf2f(r.z);
                aw_ += wgt * bf2f(r.w);
            }
        }
    }
    U16x4 o{f2bf(ax), f2bf(ay), f2bf(az), f2bf(aw_)};
    *(U16x4*)&tmp[(size_t)q * 256 + m * 32 + e * 4] = o;
}

extern "C" void kernel_launch(void* const* d_in, const int* in_sizes, int n_in,
                              void* d_out, int out_size, void* d_ws, size_t ws_size,
                              hipStream_t stream) {
    const float* query  = (const float*)d_in[0];
    const float* refpts = (const float*)d_in[1];
    const float* inflat = (const float*)d_in[2];
    const float* Wv   = (const float*)d_in[5];
    const float* bv   = (const float*)d_in[6];
    const float* Woff = (const float*)d_in[7];
    const float* boff = (const float*)d_in[8];
    const float* Wa   = (const float*)d_in[9];
    const float* ba   = (const float*)d_in[10];
    const float* Wo   = (const float*)d_in[11];
    const float* bo   = (const float*)d_in[12];
    float* out = (float*)d_out;

    // workspace layout (~82 MB)
    char* ws = (char*)d_ws;
    constexpr size_t SZ16 = (size_t)NROWS * 256 * 2;   // 13,613,056
    constexpr size_t SZ32 = (size_t)NROWS * 256 * 4;   // 27,226,112
    constexpr size_t SZL  = (size_t)NROWS * 128 * 4;   // 13,613,056
    u16*   qb    = (u16*)(ws);                         // bf16 query; later tmp
    u16*   ib    = (u16*)(ws + SZ16);                  // bf16 input
    u16*   value = (u16*)(ws + 2 * SZ16);              // bf16 value
    float* offb  = (float*)(ws + 3 * SZ16);            // fp32
    float* logit = (float*)(ws + 3 * SZ16 + SZ32);     // fp32
    u16*   wb    = (u16*)(ws + 3 * SZ16 + SZ32 + SZL); // bf16 weights
    float* bcat  = (float*)(ws + 3 * SZ16 + SZ32 + SZL + 229376 * 2);
    u16*   tmp   = qb;

    const int RG = (NROWS + 63) / 64;   // 416 row-groups

    hipLaunchKernelGGL(prep_all, dim3(14190), dim3(256), 0, stream,
                       (const float4*)query, (const float4*)inflat,
                       Wv, Woff, Wa, Wo, boff, ba, qb, ib, wb, bcat);

    gemm_front<<<dim3(10, RG), dim3(256), 0, stream>>>(
        qb, ib, wb, bv, bcat, value, offb, logit, NROWS);

    hipLaunchKernelGGL(msda_sample, dim3(NROWS / 4), dim3(256), 0, stream,
                       value, refpts, offb, logit, tmp);

    gemm_out<<<dim3(4, RG), dim3(256), 0, stream>>>(
        tmp, wb + 163840, bo, out, NROWS);
}